// Round 8
// baseline (126.041 us; speedup 1.0000x reference)
//
#include <hip/hip_runtime.h>

#define BLK 256          // 4 waves
#define MT 32            // mfma tile edge
#define IA 2             // A-frags per wave
#define IB 256           // rows per block = 4 waves * 32 * IA
#define TJQ 512          // q points staged per LDS chunk
#define SJ 4             // j-slices per (dir,b)

typedef __attribute__((ext_vector_type(8))) short short8;
typedef __attribute__((ext_vector_type(16))) float f32x16;

// Pin a tuple to arch VGPRs (gfx950 unified file) so MFMA results feed v_min3
// without AGPR round-trips.
#define FORCE_V(x) asm volatile("" : "+v"(x))

__device__ __forceinline__ unsigned int fmap(float f) {
  unsigned int b = __float_as_uint(f);
  return (b & 0x80000000u) ? ~b : (b | 0x80000000u);
}
__device__ __forceinline__ float funmap(unsigned int u) {
  return __uint_as_float((u & 0x80000000u) ? (u ^ 0x80000000u) : ~u);
}
__device__ __forceinline__ unsigned short f2bf(float f) {
  unsigned int u = __float_as_uint(f);
  u += 0x7FFFu + ((u >> 16) & 1u);
  return (unsigned short)(u >> 16);
}
__device__ __forceinline__ float bf2f(unsigned short h) {
  return __uint_as_float(((unsigned int)h) << 16);
}
__device__ __forceinline__ unsigned int pk(unsigned short a, unsigned short b) {
  return (unsigned int)a | ((unsigned int)b << 16);
}

union FragU { uint4 u; short8 s; };

// D_ij = |q_j|^2 - 2 p_i.q_j via mfma_f32_32x32x16_bf16, split-bf16 compensated
// (k-slot layout verified R5-R7, absmax 0 margin). IA=2 A-frags/wave: per
// 2 ds_read_b128 -> 4 MFMAs -> 32 v_min3. Grid = 1024 blocks of 4 waves =
// exactly 4 blocks/CU co-resident (no tail) at <=128 VGPR.
__global__ __launch_bounds__(BLK, 4) void cl_mfma(
    const float* __restrict__ A, const float* __restrict__ Bp,
    unsigned int* __restrict__ umin, int N, int jslice, int Bn) {
  __shared__ uint4 sA[2][IB];   // 8 KB
  __shared__ uint4 sB[2][TJQ];  // 16 KB
  __shared__ float sNP[IB];     // 1 KB

  const int zi = blockIdx.z;
  const int dir = zi / Bn;
  const int b = zi - dir * Bn;
  const float* __restrict__ P = dir ? Bp : A;
  const float* __restrict__ Q = dir ? A : Bp;
  unsigned int* __restrict__ um = umin + ((size_t)dir * Bn + b) * N;

  const int t = threadIdx.x;
  const int ib0 = blockIdx.x * IB;
  const int jbase = blockIdx.y * jslice;
  const size_t boff = (size_t)b * 3 * N;
  const unsigned short one = 0x3F80u;  // bf16(1.0)

  // ---- stage A-vectors + |p|^2 (once; t covers all 256 rows) ----
  {
    int i = ib0 + t;
    float x = P[boff + i], y = P[boff + N + i], zz = P[boff + 2 * N + i];
    float ax = -2.f * x, ay = -2.f * y, az = -2.f * zz;
    unsigned short hx = f2bf(ax), hy = f2bf(ay), hz = f2bf(az);
    unsigned short lx = f2bf(ax - bf2f(hx)), ly = f2bf(ay - bf2f(hy)),
                   lz = f2bf(az - bf2f(hz));
    sA[0][t] = make_uint4(pk(hx, hy), pk(hz, lx), pk(ly, lz), pk(hx, hy));
    sA[1][t] = make_uint4(pk(hz, lx), pk(ly, lz), pk(one, one), pk(one, 0));
    sNP[t] = fmaf(zz, zz, fmaf(y, y, x * x));
  }
  __syncthreads();

  const int w = t >> 6, l = t & 63, m = l & 31, g = l >> 5;
  FragU a0u, a1u;
  a0u.u = sA[g][w * 64 + m];        // rows w*64 + 0..31
  a1u.u = sA[g][w * 64 + 32 + m];   // rows w*64 + 32..63
  const short8 af0 = a0u.s, af1 = a1u.s;

  float run0[16], run1[16];
  f32x16 zc;
#pragma unroll
  for (int r = 0; r < 16; ++r) { run0[r] = 3.0e38f; run1[r] = 3.0e38f; zc[r] = 0.0f; }
  FORCE_V(zc);

  const int nch = jslice / TJQ;  // 8
  // prefetch chunk 0 (2 q points per thread)
  float qx0 = Q[boff + jbase + t];
  float qy0 = Q[boff + N + jbase + t];
  float qz0 = Q[boff + 2 * N + jbase + t];
  float qx1 = Q[boff + jbase + 256 + t];
  float qy1 = Q[boff + N + jbase + 256 + t];
  float qz1 = Q[boff + 2 * N + jbase + 256 + t];

  for (int ch = 0; ch < nch; ++ch) {
    uint4 b00, b01, b10, b11;
    {
      unsigned short hx = f2bf(qx0), hy = f2bf(qy0), hz = f2bf(qz0);
      unsigned short lx = f2bf(qx0 - bf2f(hx)), ly = f2bf(qy0 - bf2f(hy)),
                     lz = f2bf(qz0 - bf2f(hz));
      float nq = fmaf(qz0, qz0, fmaf(qy0, qy0, qx0 * qx0));
      unsigned short nh = f2bf(nq);
      float r1 = nq - bf2f(nh);
      unsigned short nm = f2bf(r1);
      unsigned short nl = f2bf(r1 - bf2f(nm));
      b00 = make_uint4(pk(hx, hy), pk(hz, hx), pk(hy, hz), pk(lx, ly));
      b01 = make_uint4(pk(lz, lx), pk(ly, lz), pk(nh, nm), pk(nl, 0));
    }
    {
      unsigned short hx = f2bf(qx1), hy = f2bf(qy1), hz = f2bf(qz1);
      unsigned short lx = f2bf(qx1 - bf2f(hx)), ly = f2bf(qy1 - bf2f(hy)),
                     lz = f2bf(qz1 - bf2f(hz));
      float nq = fmaf(qz1, qz1, fmaf(qy1, qy1, qx1 * qx1));
      unsigned short nh = f2bf(nq);
      float r1 = nq - bf2f(nh);
      unsigned short nm = f2bf(r1);
      unsigned short nl = f2bf(r1 - bf2f(nm));
      b10 = make_uint4(pk(hx, hy), pk(hz, hx), pk(hy, hz), pk(lx, ly));
      b11 = make_uint4(pk(lz, lx), pk(ly, lz), pk(nh, nm), pk(nl, 0));
    }

    __syncthreads();  // previous chunk fully consumed
    sB[0][t] = b00;
    sB[1][t] = b01;
    sB[0][256 + t] = b10;
    sB[1][256 + t] = b11;
    {  // prefetch next chunk's q; latency hides under 32 MFMAs below
      int jn = (ch + 1 < nch) ? (jbase + (ch + 1) * TJQ + t) : (jbase + t);
      qx0 = Q[boff + jn];
      qy0 = Q[boff + N + jn];
      qz0 = Q[boff + 2 * N + jn];
      qx1 = Q[boff + jn + 256];
      qy1 = Q[boff + N + jn + 256];
      qz1 = Q[boff + 2 * N + jn + 256];
    }
    __syncthreads();

#pragma unroll
    for (int jt = 0; jt < TJQ / MT; jt += 2) {
      FragU ba, bb;
      ba.u = sB[g][(jt + 0) * MT + m];
      bb.u = sB[g][(jt + 1) * MT + m];
      f32x16 d0 = __builtin_amdgcn_mfma_f32_32x32x16_bf16(af0, ba.s, zc, 0, 0, 0);
      f32x16 d1 = __builtin_amdgcn_mfma_f32_32x32x16_bf16(af0, bb.s, zc, 0, 0, 0);
      FORCE_V(d0); FORCE_V(d1);
#pragma unroll
      for (int r = 0; r < 16; ++r)
        run0[r] = fminf(fminf(run0[r], d0[r]), d1[r]);  // v_min3_f32
      f32x16 d2 = __builtin_amdgcn_mfma_f32_32x32x16_bf16(af1, ba.s, zc, 0, 0, 0);
      f32x16 d3 = __builtin_amdgcn_mfma_f32_32x32x16_bf16(af1, bb.s, zc, 0, 0, 0);
      FORCE_V(d2); FORCE_V(d3);
#pragma unroll
      for (int r = 0; r < 16; ++r)
        run1[r] = fminf(fminf(run1[r], d2[r]), d3[r]);
    }
  }

  // ---- epilogue: min across 32 cols, add |p|^2, atomicMin ----
  // C/D layout (m74/m101): col=lane&31, row=(reg&3)+8*(reg>>2)+4*(lane>>5)
#pragma unroll
  for (int r = 0; r < 16; ++r) {
    float v0 = run0[r], v1 = run1[r];
#pragma unroll
    for (int sh = 1; sh <= 16; sh <<= 1) {
      v0 = fminf(v0, __shfl_xor(v0, sh));
      v1 = fminf(v1, __shfl_xor(v1, sh));
    }
    if (m == 0) {
      int row = (r & 3) + 8 * (r >> 2) + 4 * g;
      int il0 = w * 64 + row;
      int il1 = il0 + 32;
      atomicMin(&um[ib0 + il0], fmap(v0 + sNP[il0]));
      atomicMin(&um[ib0 + il1], fmap(v1 + sNP[il1]));
    }
  }
}

// Single-block final reduce: u holds complete squared distances (256 KB).
__global__ __launch_bounds__(1024) void cl_reduce(
    const unsigned int* __restrict__ u, float* __restrict__ out, int total) {
  const int t = threadIdx.x;
  const uint4* __restrict__ u4 = (const uint4*)u;
  double s = 0.0;
  for (int i = t; i < total / 4; i += 1024) {
    uint4 v = u4[i];
    s += (double)funmap(v.x) + (double)funmap(v.y) +
         (double)funmap(v.z) + (double)funmap(v.w);
  }
  for (int off = 32; off > 0; off >>= 1) s += __shfl_down(s, off, 64);
  __shared__ double sw[16];
  if ((t & 63) == 0) sw[t >> 6] = s;
  __syncthreads();
  if (t == 0) {
    double tot = 0.0;
    for (int wv = 0; wv < 16; ++wv) tot += sw[wv];
    out[0] = (float)(tot / (double)total);
  }
}

extern "C" void kernel_launch(void* const* d_in, const int* in_sizes, int n_in,
                              void* d_out, int out_size, void* d_ws, size_t ws_size,
                              hipStream_t stream) {
  const float* in_pc = (const float*)d_in[0];
  const float* tgt_pc = (const float*)d_in[1];
  const int B = 2, N = 16384;
  unsigned int* u = (unsigned int*)d_ws;  // [2][B][N] uints = 256 KB
  float* out = (float*)d_out;

  // 0xFF bytes == "+inf" under fmap ordering.
  hipMemsetAsync(u, 0xFF, (size_t)2 * B * N * sizeof(unsigned int), stream);

  const int jslice = N / SJ;             // 4096
  dim3 grid(N / IB, SJ, 2 * B);          // (64,4,4) = 1024 blocks x 256 thr
  cl_mfma<<<grid, dim3(BLK), 0, stream>>>(in_pc, tgt_pc, u, N, jslice, B);

  const int total = 2 * B * N;
  cl_reduce<<<dim3(1), dim3(1024), 0, stream>>>(u, out, total);
}

// Round 9
// 99.659 us; speedup vs baseline: 1.2647x; 1.2647x over previous
//
#include <hip/hip_runtime.h>

#define BLK 512
#define MT 32            // mfma tile edge
#define IA 2             // A-frags per wave (rows reuse factor)
#define IB 512           // rows per block = 8 waves * 32 * IA
#define TJQ 512          // q points staged per LDS chunk
#define SJ 4             // j-slices per (dir,b) -> 512 blocks, all co-resident

typedef __attribute__((ext_vector_type(8))) short short8;
typedef __attribute__((ext_vector_type(16))) float f32x16;

// Pin a tuple to arch VGPRs (gfx950 unified file) so MFMA results feed v_min3
// without AGPR round-trips. (R7 codegen: VGPR=76, zero spill.)
#define FORCE_V(x) asm volatile("" : "+v"(x))

__device__ __forceinline__ unsigned int fmap(float f) {
  unsigned int b = __float_as_uint(f);
  return (b & 0x80000000u) ? ~b : (b | 0x80000000u);
}
__device__ __forceinline__ float funmap(unsigned int u) {
  return __uint_as_float((u & 0x80000000u) ? (u ^ 0x80000000u) : ~u);
}
__device__ __forceinline__ unsigned short f2bf(float f) {
  unsigned int u = __float_as_uint(f);
  u += 0x7FFFu + ((u >> 16) & 1u);
  return (unsigned short)(u >> 16);
}
__device__ __forceinline__ float bf2f(unsigned short h) {
  return __uint_as_float(((unsigned int)h) << 16);
}
__device__ __forceinline__ unsigned int pk(unsigned short a, unsigned short b) {
  return (unsigned int)a | ((unsigned int)b << 16);
}

union FragU { uint4 u; short8 s; };

// D_ij = |q_j|^2 - 2 p_i.q_j via mfma_f32_32x32x16_bf16, split-bf16 compensated
// (k-slot layout verified R5-R8, absmax margin 0). IA=2 A-frags/wave: per
// 2 ds_read_b128 -> 4 MFMAs -> 32 v_min3. EXACT R7 kernel body (proven
// no-spill 76-VGPR codegen); only the grid changed: 512 blocks = fully
// co-resident in ONE dispatch round (3-resident capacity is 768).
__global__ __launch_bounds__(BLK, 2) void cl_mfma(
    const float* __restrict__ A, const float* __restrict__ Bp,
    unsigned int* __restrict__ umin, int N, int jslice, int Bn) {
  __shared__ uint4 sA[2][IB];   // A-vec halves [g][row]
  __shared__ uint4 sB[2][TJQ];  // B-vec halves [g][point]
  __shared__ float sNP[IB];     // |p|^2 per row

  const int zi = blockIdx.z;
  const int dir = zi / Bn;
  const int b = zi - dir * Bn;
  const float* __restrict__ P = dir ? Bp : A;
  const float* __restrict__ Q = dir ? A : Bp;
  unsigned int* __restrict__ um = umin + ((size_t)dir * Bn + b) * N;

  const int t = threadIdx.x;
  const int ib0 = blockIdx.x * IB;
  const int jbase = blockIdx.y * jslice;
  const size_t boff = (size_t)b * 3 * N;
  const unsigned short one = 0x3F80u;  // bf16(1.0)

  // ---- stage A-vectors + |p|^2 (once) ----
  {
    int i = ib0 + t;
    float x = P[boff + i], y = P[boff + N + i], zz = P[boff + 2 * N + i];
    float ax = -2.f * x, ay = -2.f * y, az = -2.f * zz;
    unsigned short hx = f2bf(ax), hy = f2bf(ay), hz = f2bf(az);
    unsigned short lx = f2bf(ax - bf2f(hx)), ly = f2bf(ay - bf2f(hy)),
                   lz = f2bf(az - bf2f(hz));
    sA[0][t] = make_uint4(pk(hx, hy), pk(hz, lx), pk(ly, lz), pk(hx, hy));
    sA[1][t] = make_uint4(pk(hz, lx), pk(ly, lz), pk(one, one), pk(one, 0));
    sNP[t] = fmaf(zz, zz, fmaf(y, y, x * x));
  }
  __syncthreads();

  const int w = t >> 6, l = t & 63, m = l & 31, g = l >> 5;
  FragU a0u, a1u;
  a0u.u = sA[g][w * (MT * IA) + m];        // rows w*64 + 0..31
  a1u.u = sA[g][w * (MT * IA) + MT + m];   // rows w*64 + 32..63
  const short8 af0 = a0u.s, af1 = a1u.s;

  float run0[16], run1[16];
  f32x16 zc;
#pragma unroll
  for (int r = 0; r < 16; ++r) { run0[r] = 3.0e38f; run1[r] = 3.0e38f; zc[r] = 0.0f; }
  FORCE_V(zc);

  const int nch = jslice / TJQ;  // 8
  float qx = Q[boff + jbase + t];
  float qy = Q[boff + N + jbase + t];
  float qz = Q[boff + 2 * N + jbase + t];

  for (int ch = 0; ch < nch; ++ch) {
    unsigned short hx = f2bf(qx), hy = f2bf(qy), hz = f2bf(qz);
    unsigned short lx = f2bf(qx - bf2f(hx)), ly = f2bf(qy - bf2f(hy)),
                   lz = f2bf(qz - bf2f(hz));
    float nq = fmaf(qz, qz, fmaf(qy, qy, qx * qx));
    unsigned short nh = f2bf(nq);
    float r1 = nq - bf2f(nh);
    unsigned short nm = f2bf(r1);
    unsigned short nl = f2bf(r1 - bf2f(nm));
    uint4 b0s = make_uint4(pk(hx, hy), pk(hz, hx), pk(hy, hz), pk(lx, ly));
    uint4 b1s = make_uint4(pk(lz, lx), pk(ly, lz), pk(nh, nm), pk(nl, 0));

    __syncthreads();  // previous chunk fully consumed
    sB[0][t] = b0s;
    sB[1][t] = b1s;
    {  // prefetch next chunk's q; latency hides under 32 MFMAs below
      int jn = (ch + 1 < nch) ? (jbase + (ch + 1) * TJQ + t) : (jbase + t);
      qx = Q[boff + jn];
      qy = Q[boff + N + jn];
      qz = Q[boff + 2 * N + jn];
    }
    __syncthreads();

#pragma unroll
    for (int jt = 0; jt < TJQ / MT; jt += 2) {
      FragU ba, bb;
      ba.u = sB[g][(jt + 0) * MT + m];
      bb.u = sB[g][(jt + 1) * MT + m];
      f32x16 d0 = __builtin_amdgcn_mfma_f32_32x32x16_bf16(af0, ba.s, zc, 0, 0, 0);
      f32x16 d1 = __builtin_amdgcn_mfma_f32_32x32x16_bf16(af0, bb.s, zc, 0, 0, 0);
      FORCE_V(d0); FORCE_V(d1);
#pragma unroll
      for (int r = 0; r < 16; ++r)
        run0[r] = fminf(fminf(run0[r], d0[r]), d1[r]);  // v_min3_f32
      f32x16 d2 = __builtin_amdgcn_mfma_f32_32x32x16_bf16(af1, ba.s, zc, 0, 0, 0);
      f32x16 d3 = __builtin_amdgcn_mfma_f32_32x32x16_bf16(af1, bb.s, zc, 0, 0, 0);
      FORCE_V(d2); FORCE_V(d3);
#pragma unroll
      for (int r = 0; r < 16; ++r)
        run1[r] = fminf(fminf(run1[r], d2[r]), d3[r]);
    }
  }

  // ---- epilogue: min across 32 cols, add |p|^2, atomicMin ----
  // C/D layout (m74/m101): col=lane&31, row=(reg&3)+8*(reg>>2)+4*(lane>>5)
#pragma unroll
  for (int r = 0; r < 16; ++r) {
    float v0 = run0[r], v1 = run1[r];
#pragma unroll
    for (int sh = 1; sh <= 16; sh <<= 1) {
      v0 = fminf(v0, __shfl_xor(v0, sh));
      v1 = fminf(v1, __shfl_xor(v1, sh));
    }
    if (m == 0) {
      int row = (r & 3) + 8 * (r >> 2) + 4 * g;
      int il0 = w * (MT * IA) + row;
      int il1 = il0 + MT;
      atomicMin(&um[ib0 + il0], fmap(v0 + sNP[il0]));
      atomicMin(&um[ib0 + il1], fmap(v1 + sNP[il1]));
    }
  }
}

// Parallel final reduce: u holds complete squared distances (256 KB).
// 16 blocks; per-block double partial -> one pre-scaled float atomicAdd.
__global__ __launch_bounds__(256) void cl_reduce(
    const unsigned int* __restrict__ u, float* __restrict__ out, int total) {
  const int t = threadIdx.x;
  const uint4* __restrict__ u4 = (const uint4*)u;
  const int n4 = total / 4;
  const int gid = blockIdx.x * 256 + t;
  const int gstride = gridDim.x * 256;
  double s = 0.0;
  for (int i = gid; i < n4; i += gstride) {
    uint4 v = u4[i];
    s += (double)funmap(v.x) + (double)funmap(v.y) +
         (double)funmap(v.z) + (double)funmap(v.w);
  }
  for (int off = 32; off > 0; off >>= 1) s += __shfl_down(s, off, 64);
  __shared__ double sw[4];
  if ((t & 63) == 0) sw[t >> 6] = s;
  __syncthreads();
  if (t == 0) {
    double tot = sw[0] + sw[1] + sw[2] + sw[3];
    atomicAdd(out, (float)(tot / (double)total));
  }
}

extern "C" void kernel_launch(void* const* d_in, const int* in_sizes, int n_in,
                              void* d_out, int out_size, void* d_ws, size_t ws_size,
                              hipStream_t stream) {
  const float* in_pc = (const float*)d_in[0];
  const float* tgt_pc = (const float*)d_in[1];
  const int B = 2, N = 16384;
  unsigned int* u = (unsigned int*)d_ws;  // [2][B][N] uints = 256 KB
  float* out = (float*)d_out;

  // 0xFF bytes == "+inf" under fmap ordering; out accumulates partials.
  hipMemsetAsync(u, 0xFF, (size_t)2 * B * N * sizeof(unsigned int), stream);
  hipMemsetAsync(out, 0, sizeof(float), stream);

  const int jslice = N / SJ;             // 4096
  dim3 grid(N / IB, SJ, 2 * B);          // (32,4,4) = 512 blocks x 512 thr
  cl_mfma<<<grid, dim3(BLK), 0, stream>>>(in_pc, tgt_pc, u, N, jslice, B);

  const int total = 2 * B * N;
  cl_reduce<<<dim3(16), dim3(256), 0, stream>>>(u, out, total);
}